// Round 3
// baseline (426.642 us; speedup 1.0000x reference)
//
#include <hip/hip_runtime.h>

#define BB 8
#define CC 256
#define DD 128
#define NN 4096

#define LOG2E 1.44269504f
#define MSHIFT 32.0f  // fixed softmax shift (base-2 domain); |S*log2e| << 32 always

typedef __attribute__((ext_vector_type(8))) short short8;
typedef __attribute__((ext_vector_type(4))) short short4v;
typedef __attribute__((ext_vector_type(4))) float f32x4;
typedef __attribute__((ext_vector_type(16))) float f32x16;
typedef __attribute__((ext_vector_type(4))) unsigned int u32x4;

static __device__ __forceinline__ unsigned short f2bf(float f) {
    unsigned u = __builtin_bit_cast(unsigned, f);
    u += 0x7FFFu + ((u >> 16) & 1u);
    return (unsigned short)(u >> 16);
}
static __device__ __forceinline__ float bf2f(unsigned short h) {
    unsigned u = ((unsigned)h) << 16;
    return __builtin_bit_cast(float, u);
}
static __device__ __forceinline__ short8 pack8(float4 a, float4 b) {
    short8 r;
    r[0] = (short)f2bf(a.x); r[1] = (short)f2bf(a.y);
    r[2] = (short)f2bf(a.z); r[3] = (short)f2bf(a.w);
    r[4] = (short)f2bf(b.x); r[5] = (short)f2bf(b.y);
    r[6] = (short)f2bf(b.z); r[7] = (short)f2bf(b.w);
    return r;
}
// packed f32x2 -> bf16x2 (RNE); element 0 in low 16 bits
static __device__ __forceinline__ unsigned cvtpk_bf16(float lo, float hi) {
    unsigned r;
    asm("v_cvt_pk_bf16_f32 %0, %1, %2" : "=v"(r) : "v"(lo), "v"(hi));
    return r;
}
// swap upper 32 lanes of a with lower 32 lanes of b (T12 primitive)
static __device__ __forceinline__ void pl32swap(unsigned &a, unsigned &b) {
#if __has_builtin(__builtin_amdgcn_permlane32_swap)
    auto r = __builtin_amdgcn_permlane32_swap((int)a, (int)b, false, false);
    a = (unsigned)r[0]; b = (unsigned)r[1];
#else
    asm("v_permlane32_swap_b32 %0, %1" : "+v"(a), "+v"(b));
#endif
}

// ---------------- kernel 1: x fp32 [b][c][n] -> xT bf16 [b][n][c] ----------------
// grid (NN/64, CC/64, BB), block 256
__global__ __launch_bounds__(256) void k_transpose_x(
        const float* __restrict__ x, unsigned short* __restrict__ xT) {
    __shared__ __align__(16) unsigned short tile[64][66];
    int nb = blockIdx.x * 64, cb = blockIdx.y * 64, b = blockIdx.z;
    const float* xp = x + (size_t)b * CC * NN;
    int t = threadIdx.x;
#pragma unroll
    for (int i = 0; i < 2; i++) {
        int idx = t + 256 * i;
        int c_l = idx >> 3;
        int n0 = (idx & 7) * 8;
        const float* src = xp + (size_t)(cb + c_l) * NN + nb + n0;
        float4 v0 = *(const float4*)(src);
        float4 v1 = *(const float4*)(src + 4);
        tile[n0 + 0][c_l] = f2bf(v0.x);
        tile[n0 + 1][c_l] = f2bf(v0.y);
        tile[n0 + 2][c_l] = f2bf(v0.z);
        tile[n0 + 3][c_l] = f2bf(v0.w);
        tile[n0 + 4][c_l] = f2bf(v1.x);
        tile[n0 + 5][c_l] = f2bf(v1.y);
        tile[n0 + 6][c_l] = f2bf(v1.z);
        tile[n0 + 7][c_l] = f2bf(v1.w);
    }
    __syncthreads();
    unsigned short* xtp = xT + (size_t)b * NN * CC;
#pragma unroll
    for (int i = 0; i < 2; i++) {
        int idx = t + 256 * i;
        int n_l = idx >> 3;
        int c0 = (idx & 7) * 8;
        const unsigned int* row = (const unsigned int*)&tile[n_l][0];
        uint4 o;
        o.x = row[(c0 >> 1) + 0];
        o.y = row[(c0 >> 1) + 1];
        o.z = row[(c0 >> 1) + 2];
        o.w = row[(c0 >> 1) + 3];
        *(uint4*)(xtp + (size_t)(nb + n_l) * CC + cb + c0) = o;
    }
}

// ---------------- kernel 2: projections (x staged in LDS; coalesced stores) ----------------
// proj 0: theta*log2e -> Q[n][d]; proj 1: phi -> K[n][d]; proj 2: g -> Vt[d][n]
// grid (NN/128, 3, BB), block 256 (4 waves; wave owns d-range wave*32..+32)
__global__ __launch_bounds__(256) void k_proj(
        const unsigned short* __restrict__ xT,
        const float* __restrict__ w_phi, const float* __restrict__ b_phi,
        const float* __restrict__ w_theta, const float* __restrict__ b_theta,
        const float* __restrict__ w_g, const float* __restrict__ b_g,
        unsigned short* __restrict__ qws, unsigned short* __restrict__ kws,
        unsigned short* __restrict__ vtws) {
    __shared__ __align__(16) unsigned short xs[128][72];     // staged x chunk [n][64c]
    __shared__ __align__(16) unsigned short rp[128][136];    // repack buffer
    int nb = blockIdx.x * 128, proj = blockIdx.y, b = blockIdx.z;
    const float *W, *bias;
    if (proj == 0) { W = w_theta; bias = b_theta; }
    else if (proj == 1) { W = w_phi; bias = b_phi; }
    else { W = w_g; bias = b_g; }
    float scl = (proj == 0) ? LOG2E : 1.0f;
    int t = threadIdx.x, lane = t & 63, wave = t >> 6;
    int l16 = lane & 15, l4 = lane >> 4;

    f32x4 acc[2][8];
#pragma unroll
    for (int mf = 0; mf < 2; mf++)
#pragma unroll
        for (int nf = 0; nf < 8; nf++)
#pragma unroll
            for (int e = 0; e < 4; e++) acc[mf][nf][e] = 0.f;

    const unsigned short* xtp = xT + (size_t)b * NN * CC;
    for (int kc = 0; kc < 4; kc++) {
        int c0k = kc * 64;
        __syncthreads();
#pragma unroll
        for (int i = 0; i < 4; i++) {  // stage [128 n][64 c]
            int idx = t + 256 * i;
            int n = idx >> 3, cc = (idx & 7) * 8;
            *(short8*)&xs[n][cc] = *(const short8*)(xtp + (size_t)(nb + n) * CC + c0k + cc);
        }
        __syncthreads();
        short8 af[2][2];
#pragma unroll
        for (int mf = 0; mf < 2; mf++)
#pragma unroll
            for (int ic = 0; ic < 2; ic++) {
                int d = wave * 32 + mf * 16 + l16;
                const float* wp = W + d * CC + c0k + ic * 32 + l4 * 8;
                af[mf][ic] = pack8(*(const float4*)wp, *(const float4*)(wp + 4));
            }
#pragma unroll
        for (int nf = 0; nf < 8; nf++)
#pragma unroll
            for (int ic = 0; ic < 2; ic++) {
                short8 bfr = *(const short8*)&xs[nf * 16 + l16][ic * 32 + l4 * 8];
                acc[0][nf] = __builtin_amdgcn_mfma_f32_16x16x32_bf16(af[0][ic], bfr, acc[0][nf], 0, 0, 0);
                acc[1][nf] = __builtin_amdgcn_mfma_f32_16x16x32_bf16(af[1][ic], bfr, acc[1][nf], 0, 0, 0);
            }
    }
    // acc C-layout: col(l16) = n-within-frag, row(l4*4+r) = d-within-frag
    __syncthreads();  // xs done; rp reuse safe
    if (proj < 2) {
        unsigned short* outp = (proj == 0 ? qws : kws) + (size_t)b * NN * DD;
#pragma unroll
        for (int mf = 0; mf < 2; mf++) {
            int d0 = wave * 32 + mf * 16 + l4 * 4;
            float bb[4];
#pragma unroll
            for (int r = 0; r < 4; r++) bb[r] = bias[d0 + r];
#pragma unroll
            for (int nf = 0; nf < 8; nf++) {
                short4v pk;
#pragma unroll
                for (int r = 0; r < 4; r++) pk[r] = (short)f2bf((acc[mf][nf][r] + bb[r]) * scl);
                *(short4v*)&rp[nf * 16 + l16][d0] = pk;
            }
        }
        __syncthreads();
#pragma unroll
        for (int i = 0; i < 8; i++) {
            int idx = t + 256 * i;
            int n = idx >> 4, dd = (idx & 15) * 8;
            *(short8*)(outp + (size_t)(nb + n) * DD + dd) = *(const short8*)&rp[n][dd];
        }
    } else {
#pragma unroll
        for (int mf = 0; mf < 2; mf++) {
            int drow = wave * 32 + mf * 16 + l4 * 4;
            float bb[4];
#pragma unroll
            for (int r = 0; r < 4; r++) bb[r] = bias[drow + r];
#pragma unroll
            for (int nf = 0; nf < 8; nf++)
#pragma unroll
                for (int r = 0; r < 4; r++)
                    rp[drow + r][nf * 16 + l16] = f2bf(acc[mf][nf][r] + bb[r]);
        }
        __syncthreads();
        unsigned short* outp = vtws + (size_t)b * DD * NN;
#pragma unroll
        for (int i = 0; i < 8; i++) {
            int idx = t + 256 * i;
            int d = idx >> 4, n0 = (idx & 15) * 8;
            *(short8*)(outp + (size_t)d * NN + nb + n0) = *(const short8*)&rp[d][n0];
        }
    }
}

// ---------------- kernel 3: flash attention — 2-wave blocks, T15 pipelined ----------------
// grid 1024 = 8 b x 2 ks x 64 q-tiles (4 independent blocks/CU). Wave owns 32 q-rows.
// KVBLK = 32, NIT = 64. Swapped QK^T (S^T = mfma(K,Q)); softmax lane-local; PV A-frags
// in-register via cvt_pk_bf16 + permlane32_swap (T12).
// T15 pipeline: iteration t interleaves softmax(t)+PV(t) with QK^T(t+1) — the 16 QK MFMAs
// have no dep on softmax, so the matrix pipe stays fed during the exp2/cvt VALU phase.
// Ping-pong S-accumulators (static indexing); final iter's QK^T computes discarded values.
// LDS: double-buffered K (32x256B, swz ^(row&7)) + V (128x64B, swz ^((row^row>>2)&3)).
// Two barriers/iter: [compute] bar [write tile t+2 over tile t] bar.
__global__ __launch_bounds__(128, 2) void k_flash(
        const unsigned short* __restrict__ q, const unsigned short* __restrict__ kk,
        const unsigned short* __restrict__ vt, unsigned short* __restrict__ opart,
        float* __restrict__ lsums) {
    __shared__ __align__(16) unsigned char smem[32768];
    // K[buf] at buf*8192 (32 rows x 256 B); V[buf] at 16384 + buf*8192 (128 rows x 64 B)

    int bid = blockIdx.x;
    int b   = bid & 7;           // batch -> XCD (round-robin dispatch): K/V L2-resident
    int rem = bid >> 3;
    int ks  = rem >> 6;
    int qt  = rem & 63;
    int qb  = qt * 64;

    int t = threadIdx.x, lane = t & 63, wave = t >> 6;
    int l31 = lane & 31, hi = lane >> 5;

    const unsigned short* qp = q  + (size_t)b * NN * DD;
    const unsigned short* kp = kk + (size_t)b * NN * DD;
    const unsigned short* vp = vt + (size_t)b * DD * NN;

    // Q fragments (B-operand of swapped QK^T): lane holds Q[qb+w*32+l31][kc*16+hi*8+e]
    short8 qreg[8];
    {
        int qrow = qb + wave * 32 + l31;
#pragma unroll
        for (int kc = 0; kc < 8; kc++)
            qreg[kc] = *(const short8*)(qp + (size_t)qrow * DD + kc * 16 + hi * 8);
    }

    f32x16 o[4];
#pragma unroll
    for (int df = 0; df < 4; df++)
#pragma unroll
        for (int e = 0; e < 16; e++) o[df][e] = 0.f;
    float lsum0 = 0.f, lsum1 = 0.f;

    int kbase = ks * (NN / 2);
    const int NIT = (NN / 2) / 32;  // 64

    // prologue: stage tiles 0 and 1 into buffers 0 and 1
#pragma unroll
    for (int pt = 0; pt < 2; pt++) {
        uint4 k0[4], v0[4];
        int mb = kbase + pt * 32;
#pragma unroll
        for (int i = 0; i < 4; i++) {
            int idx = t + 128 * i;  // 0..511
            k0[i] = *(const uint4*)(kp + (size_t)(mb + (idx >> 4)) * DD + (idx & 15) * 8);
            v0[i] = *(const uint4*)(vp + (size_t)(idx >> 2) * NN + mb + (idx & 3) * 8);
        }
        char* Kb = (char*)smem + pt * 8192;
        char* Vb = (char*)smem + 16384 + pt * 8192;
#pragma unroll
        for (int i = 0; i < 4; i++) {
            int idx = t + 128 * i;
            int rk = idx >> 4, ck = idx & 15;
            *(uint4*)(Kb + rk * 256 + ((ck ^ (rk & 7)) << 4)) = k0[i];
            int rv = idx >> 2, cv = idx & 3;
            *(uint4*)(Vb + rv * 64 + ((cv ^ ((rv ^ (rv >> 2)) & 3)) << 4)) = v0[i];
        }
    }
    __syncthreads();

    // QK^T(0) from buffer 0
    f32x16 sA, sB, sA2, sB2;
#pragma unroll
    for (int e = 0; e < 16; e++) { sA[e] = -MSHIFT; sB[e] = 0.f; }
    {
        char* Kb = (char*)smem;
        __builtin_amdgcn_s_setprio(1);
#pragma unroll
        for (int kc = 0; kc < 8; kc += 2) {
            short8 a0 = *(const short8*)(Kb + l31 * 256 + ((((kc << 1) | hi) ^ (l31 & 7)) << 4));
            short8 a1 = *(const short8*)(Kb + l31 * 256 + (((((kc + 1) << 1) | hi) ^ (l31 & 7)) << 4));
            sA = __builtin_amdgcn_mfma_f32_32x32x16_bf16(a0, qreg[kc], sA, 0, 0, 0);
            sB = __builtin_amdgcn_mfma_f32_32x32x16_bf16(a1, qreg[kc + 1], sB, 0, 0, 0);
        }
        __builtin_amdgcn_s_setprio(0);
    }

    // pipelined body: softmax(it)+PV(it) interleaved with QK^T(it+1)
    auto body = [&](int it, f32x16& sAc, f32x16& sBc, f32x16& sAn, f32x16& sBn) {
        char* KbN = (char*)smem + ((it + 1) & 1) * 8192;        // K of tile it+1
        char* Vb  = (char*)smem + 16384 + (it & 1) * 8192;      // V of tile it
        char* KbW = (char*)smem + (it & 1) * 8192;              // write dest (tile it+2)
        char* VbW = (char*)smem + 16384 + (it & 1) * 8192;

        // T14: issue tile it+2's global loads; latency covered by full compute phase
        uint4 kr[4], vr[4];
        bool pf = (it + 2 < NIT);
        if (pf) {
            int mb2 = kbase + (it + 2) * 32;
#pragma unroll
            for (int i = 0; i < 4; i++) {
                int idx = t + 128 * i;
                kr[i] = *(const uint4*)(kp + (size_t)(mb2 + (idx >> 4)) * DD + (idx & 15) * 8);
                vr[i] = *(const uint4*)(vp + (size_t)(idx >> 2) * NN + mb2 + (idx & 3) * 8);
            }
        }

#pragma unroll
        for (int e = 0; e < 16; e++) { sAn[e] = -MSHIFT; sBn[e] = 0.f; }

        float p[16];
        u32x4 pa[2];
        __builtin_amdgcn_s_setprio(1);
        // groups 0,1: p[0..7] interleaved with QK(it+1) kc 0..3
#pragma unroll
        for (int g = 0; g < 2; g++) {
#pragma unroll
            for (int r = 4 * g; r < 4 * g + 4; r++) {
                p[r] = __builtin_exp2f(sAc[r] + sBc[r]);
                if (r & 1) lsum1 += p[r]; else lsum0 += p[r];
            }
            int kc = 2 * g;
            short8 a0 = *(const short8*)(KbN + l31 * 256 + ((((kc << 1) | hi) ^ (l31 & 7)) << 4));
            short8 a1 = *(const short8*)(KbN + l31 * 256 + (((((kc + 1) << 1) | hi) ^ (l31 & 7)) << 4));
            sAn = __builtin_amdgcn_mfma_f32_32x32x16_bf16(a0, qreg[kc], sAn, 0, 0, 0);
            sBn = __builtin_amdgcn_mfma_f32_32x32x16_bf16(a1, qreg[kc + 1], sBn, 0, 0, 0);
        }
        {   // pa[0] from p[0..7]
            unsigned a0 = cvtpk_bf16(p[0], p[1]);
            unsigned a1 = cvtpk_bf16(p[2], p[3]);
            unsigned b0 = cvtpk_bf16(p[4], p[5]);
            unsigned b1 = cvtpk_bf16(p[6], p[7]);
            pl32swap(a0, b0);
            pl32swap(a1, b1);
            u32x4 v; v[0] = a0; v[1] = a1; v[2] = b0; v[3] = b1;
            pa[0] = v;
        }
        // groups 2,3: p[8..15] interleaved with QK(it+1) kc 4..7
#pragma unroll
        for (int g = 2; g < 4; g++) {
#pragma unroll
            for (int r = 4 * g; r < 4 * g + 4; r++) {
                p[r] = __builtin_exp2f(sAc[r] + sBc[r]);
                if (r & 1) lsum1 += p[r]; else lsum0 += p[r];
            }
            int kc = 2 * g;
            short8 a0 = *(const short8*)(KbN + l31 * 256 + ((((kc << 1) | hi) ^ (l31 & 7)) << 4));
            short8 a1 = *(const short8*)(KbN + l31 * 256 + (((((kc + 1) << 1) | hi) ^ (l31 & 7)) << 4));
            sAn = __builtin_amdgcn_mfma_f32_32x32x16_bf16(a0, qreg[kc], sAn, 0, 0, 0);
            sBn = __builtin_amdgcn_mfma_f32_32x32x16_bf16(a1, qreg[kc + 1], sBn, 0, 0, 0);
        }
        {   // pa[1] from p[8..15]
            unsigned a0 = cvtpk_bf16(p[8], p[9]);
            unsigned a1 = cvtpk_bf16(p[10], p[11]);
            unsigned b0 = cvtpk_bf16(p[12], p[13]);
            unsigned b1 = cvtpk_bf16(p[14], p[15]);
            pl32swap(a0, b0);
            pl32swap(a1, b1);
            u32x4 v; v[0] = a0; v[1] = a1; v[2] = b0; v[3] = b1;
            pa[1] = v;
        }

        // O += P V  (V^T stored -> B-frag is a direct contiguous ds_read_b128)
#pragma unroll
        for (int df = 0; df < 4; df++) {
            int row = df * 32 + l31;
            int sw = (row ^ (row >> 2)) & 3;
#pragma unroll
            for (int c = 0; c < 2; c++) {
                short8 vb = *(const short8*)(Vb + row * 64 + ((((c << 1) | hi) ^ sw) << 4));
                o[df] = __builtin_amdgcn_mfma_f32_32x32x16_bf16(
                    __builtin_bit_cast(short8, pa[c]), vb, o[df], 0, 0, 0);
            }
        }
        __builtin_amdgcn_s_setprio(0);

        __syncthreads();  // all waves done reading tile it (K read last iter, V this iter)
        if (pf) {
#pragma unroll
            for (int i = 0; i < 4; i++) {
                int idx = t + 128 * i;
                int rk = idx >> 4, ck = idx & 15;
                *(uint4*)(KbW + rk * 256 + ((ck ^ (rk & 7)) << 4)) = kr[i];
                int rv = idx >> 2, cv = idx & 3;
                *(uint4*)(VbW + rv * 64 + ((cv ^ ((rv ^ (rv >> 2)) & 3)) << 4)) = vr[i];
            }
        }
        __syncthreads();  // tile it+2 visible for iter it+1's QK^T
    };

    for (int it = 0; it < NIT; it += 2) {
        body(it, sA, sB, sA2, sB2);
        body(it + 1, sA2, sB2, sA, sB);
    }

    // ---- epilogue: row-sums + staged coalesced O-partial store ----
    {
        float lsum = lsum0 + lsum1;
        float tot = lsum + __shfl_xor(lsum, 32);
        if (lane < 32)
            lsums[((size_t)ks * BB + b) * NN + qb + wave * 32 + l31] = tot;
    }
    unsigned short (*Ox)[136] = (unsigned short (*)[136])smem;  // 64 x 136 (17408 B)
#pragma unroll
    for (int df = 0; df < 4; df++)
#pragma unroll
        for (int r = 0; r < 16; r++) {
            int qr = (r & 3) + 8 * (r >> 2) + 4 * hi;
            Ox[wave * 32 + qr][df * 32 + l31] = f2bf(o[df][r]);
        }
    __syncthreads();
    unsigned short* op = opart + (((size_t)ks * BB + b) * NN + qb) * DD;
#pragma unroll
    for (int i = 0; i < 8; i++) {
        int idx = t + 128 * i;  // 0..1023
        int nr = idx >> 4, c0 = (idx & 15) * 8;
        *(short8*)(op + (size_t)nr * DD + c0) = *(const short8*)&Ox[nr][c0];
    }
}

// ---------------- kernel 4: combine partials + out = w_mask . y^T + b_mask + x ----------------
// grid (NN/64, 2, BB), block 256; cs = blockIdx.y picks c-range cs*128..+128
__global__ __launch_bounds__(256) void k_maskout(
        const unsigned short* __restrict__ opart, const float* __restrict__ lsums,
        const float* __restrict__ w_mask, const float* __restrict__ b_mask,
        const float* __restrict__ x, float* __restrict__ out) {
    __shared__ __align__(16) unsigned short Ys[64][136];
    __shared__ float invl[64];
    int nb = blockIdx.x * 64, cs = blockIdx.y, b = blockIdx.z;
    int t = threadIdx.x, lane = t & 63, wave = t >> 6;
    int l16 = lane & 15, l4 = lane >> 4;

    const unsigned short* o0 = opart + ((size_t)b * NN + nb) * DD;
    const unsigned short* o1 = opart + (((size_t)BB + b) * NN + nb) * DD;
    if (t < 64) {
        float ls0 = lsums[(size_t)b * NN + nb + t];
        float ls1 = lsums[((size_t)BB + b) * NN + nb + t];
        invl[t] = 1.0f / (ls0 + ls1);
    }
    __syncthreads();
#pragma unroll
    for (int i = 0; i < 4; i++) {  // combine the 2 key-split partials while staging y
        int idx = t + 256 * i;
        int nr = idx >> 4, d0 = (idx & 15) * 8;
        short8 a = *(const short8*)(o0 + (size_t)nr * DD + d0);
        short8 c = *(const short8*)(o1 + (size_t)nr * DD + d0);
        float inv = invl[nr];
        short8 yv;
#pragma unroll
        for (int j = 0; j < 8; j++)
            yv[j] = (short)f2bf((bf2f((unsigned short)a[j]) + bf2f((unsigned short)c[j])) * inv);
        *(short8*)&Ys[nr][d0] = yv;
    }
    __syncthreads();

    f32x4 acc[2][4];
#pragma unroll
    for (int mf = 0; mf < 2; mf++)
#pragma unroll
        for (int nf = 0; nf < 4; nf++)
#pragma unroll
            for (int e = 0; e < 4; e++) acc[mf][nf][e] = 0.f;

#pragma unroll
    for (int kc = 0; kc < 4; kc++) {
        int d0 = kc * 32 + l4 * 8;
        short8 af[2];
#pragma unroll
        for (int mf = 0; mf < 2; mf++) {
            int c = cs * 128 + wave * 32 + mf * 16 + l16;
            const float* wp = w_mask + c * DD + d0;
            af[mf] = pack8(*(const float4*)wp, *(const float4*)(wp + 4));
        }
#pragma unroll
        for (int nf = 0; nf < 4; nf++) {
            short8 bfr = *(const short8*)&Ys[nf * 16 + l16][d0];
#pragma unroll
            for (int mf = 0; mf < 2; mf++)
                acc[mf][nf] = __builtin_amdgcn_mfma_f32_16x16x32_bf16(af[mf], bfr, acc[mf][nf], 0, 0, 0);
        }
    }

    const float* xp = x + (size_t)b * CC * NN;
    float* op = out + (size_t)b * CC * NN;
#pragma unroll
    for (int mf = 0; mf < 2; mf++) {
        int c0 = cs * 128 + wave * 32 + mf * 16 + l4 * 4;
        float bb[4];
#pragma unroll
        for (int r = 0; r < 4; r++) bb[r] = b_mask[c0 + r];
#pragma unroll
        for (int r = 0; r < 4; r++) {
            size_t rowoff = (size_t)(c0 + r) * NN;
#pragma unroll
            for (int nf = 0; nf < 4; nf++) {
                int n = nb + nf * 16 + l16;
                op[rowoff + n] = acc[mf][nf][r] + bb[r] + xp[rowoff + n];
            }
        }
    }
}

extern "C" void kernel_launch(void* const* d_in, const int* in_sizes, int n_in,
                              void* d_out, int out_size, void* d_ws, size_t ws_size,
                              hipStream_t stream) {
    const float* x       = (const float*)d_in[0];
    const float* w_phi   = (const float*)d_in[1];
    const float* b_phi   = (const float*)d_in[2];
    const float* w_theta = (const float*)d_in[3];
    const float* b_theta = (const float*)d_in[4];
    const float* w_g     = (const float*)d_in[5];
    const float* b_g     = (const float*)d_in[6];
    const float* w_mask  = (const float*)d_in[7];
    const float* b_mask  = (const float*)d_in[8];
    float* out = (float*)d_out;

    // ws (48 MiB): [0,16M): xT (dead after k_proj) -> reused as Opart (2*8*4096*128 bf16 = 16 MiB)
    //              [16,24M): Q | [24,32M): K | [32,40M): Vt | [40M+): lsums (2*8*4096 fp32 = 256 KiB)
    char* ws = (char*)d_ws;
    unsigned short* xT    = (unsigned short*)(ws);
    unsigned short* opart = (unsigned short*)(ws);  // overlays xT after proj
    unsigned short* qw    = (unsigned short*)(ws + ((size_t)16 << 20));
    unsigned short* kw    = (unsigned short*)(ws + ((size_t)24 << 20));
    unsigned short* vtw   = (unsigned short*)(ws + ((size_t)32 << 20));
    float*          lsums = (float*)(ws + ((size_t)40 << 20));

    k_transpose_x<<<dim3(NN / 64, CC / 64, BB), 256, 0, stream>>>(x, xT);
    k_proj<<<dim3(NN / 128, 3, BB), 256, 0, stream>>>(xT, w_phi, b_phi, w_theta, b_theta,
                                                      w_g, b_g, qw, kw, vtw);
    k_flash<<<dim3(1024, 1, 1), 128, 0, stream>>>(qw, kw, vtw, opart, lsums);
    k_maskout<<<dim3(NN / 64, 2, BB), 256, 0, stream>>>(opart, lsums, w_mask, b_mask, x, out);
}

// Round 4
// 295.246 us; speedup vs baseline: 1.4450x; 1.4450x over previous
//
#include <hip/hip_runtime.h>

#define BB 8
#define CC 256
#define DD 128
#define NN 4096

#define LOG2E 1.44269504f
#define MSHIFT 32.0f  // fixed softmax shift (base-2 domain); |S*log2e| << 32 always

typedef __attribute__((ext_vector_type(8))) short short8;
typedef __attribute__((ext_vector_type(4))) short short4v;
typedef __attribute__((ext_vector_type(4))) float f32x4;
typedef __attribute__((ext_vector_type(16))) float f32x16;
typedef __attribute__((ext_vector_type(4))) unsigned int u32x4;

static __device__ __forceinline__ unsigned short f2bf(float f) {
    unsigned u = __builtin_bit_cast(unsigned, f);
    u += 0x7FFFu + ((u >> 16) & 1u);
    return (unsigned short)(u >> 16);
}
static __device__ __forceinline__ float bf2f(unsigned short h) {
    unsigned u = ((unsigned)h) << 16;
    return __builtin_bit_cast(float, u);
}
static __device__ __forceinline__ short8 pack8(float4 a, float4 b) {
    short8 r;
    r[0] = (short)f2bf(a.x); r[1] = (short)f2bf(a.y);
    r[2] = (short)f2bf(a.z); r[3] = (short)f2bf(a.w);
    r[4] = (short)f2bf(b.x); r[5] = (short)f2bf(b.y);
    r[6] = (short)f2bf(b.z); r[7] = (short)f2bf(b.w);
    return r;
}
// packed f32x2 -> bf16x2 (RNE); element 0 in low 16 bits
static __device__ __forceinline__ unsigned cvtpk_bf16(float lo, float hi) {
    unsigned r;
    asm("v_cvt_pk_bf16_f32 %0, %1, %2" : "=v"(r) : "v"(lo), "v"(hi));
    return r;
}
// swap upper 32 lanes of a with lower 32 lanes of b (T12 primitive)
static __device__ __forceinline__ void pl32swap(unsigned &a, unsigned &b) {
#if __has_builtin(__builtin_amdgcn_permlane32_swap)
    auto r = __builtin_amdgcn_permlane32_swap((int)a, (int)b, false, false);
    a = (unsigned)r[0]; b = (unsigned)r[1];
#else
    asm("v_permlane32_swap_b32 %0, %1" : "+v"(a), "+v"(b));
#endif
}

// ---------------- kernel 1: x fp32 [b][c][n] -> xT bf16 [b][n][c] ----------------
// grid (NN/64, CC/64, BB), block 256
__global__ __launch_bounds__(256) void k_transpose_x(
        const float* __restrict__ x, unsigned short* __restrict__ xT) {
    __shared__ __align__(16) unsigned short tile[64][66];
    int nb = blockIdx.x * 64, cb = blockIdx.y * 64, b = blockIdx.z;
    const float* xp = x + (size_t)b * CC * NN;
    int t = threadIdx.x;
#pragma unroll
    for (int i = 0; i < 2; i++) {
        int idx = t + 256 * i;
        int c_l = idx >> 3;
        int n0 = (idx & 7) * 8;
        const float* src = xp + (size_t)(cb + c_l) * NN + nb + n0;
        float4 v0 = *(const float4*)(src);
        float4 v1 = *(const float4*)(src + 4);
        tile[n0 + 0][c_l] = f2bf(v0.x);
        tile[n0 + 1][c_l] = f2bf(v0.y);
        tile[n0 + 2][c_l] = f2bf(v0.z);
        tile[n0 + 3][c_l] = f2bf(v0.w);
        tile[n0 + 4][c_l] = f2bf(v1.x);
        tile[n0 + 5][c_l] = f2bf(v1.y);
        tile[n0 + 6][c_l] = f2bf(v1.z);
        tile[n0 + 7][c_l] = f2bf(v1.w);
    }
    __syncthreads();
    unsigned short* xtp = xT + (size_t)b * NN * CC;
#pragma unroll
    for (int i = 0; i < 2; i++) {
        int idx = t + 256 * i;
        int n_l = idx >> 3;
        int c0 = (idx & 7) * 8;
        const unsigned int* row = (const unsigned int*)&tile[n_l][0];
        uint4 o;
        o.x = row[(c0 >> 1) + 0];
        o.y = row[(c0 >> 1) + 1];
        o.z = row[(c0 >> 1) + 2];
        o.w = row[(c0 >> 1) + 3];
        *(uint4*)(xtp + (size_t)(nb + n_l) * CC + cb + c0) = o;
    }
}

// ---------------- kernel 2: projections (x staged in LDS; coalesced stores) ----------------
// proj 0: theta*log2e -> Q[n][d]; proj 1: phi -> K[n][d]; proj 2: g -> Vt[d][n]
// grid (NN/128, 3, BB), block 256 (4 waves; wave owns d-range wave*32..+32)
__global__ __launch_bounds__(256) void k_proj(
        const unsigned short* __restrict__ xT,
        const float* __restrict__ w_phi, const float* __restrict__ b_phi,
        const float* __restrict__ w_theta, const float* __restrict__ b_theta,
        const float* __restrict__ w_g, const float* __restrict__ b_g,
        unsigned short* __restrict__ qws, unsigned short* __restrict__ kws,
        unsigned short* __restrict__ vtws) {
    __shared__ __align__(16) unsigned short xs[128][72];     // staged x chunk [n][64c]
    __shared__ __align__(16) unsigned short rp[128][136];    // repack buffer
    int nb = blockIdx.x * 128, proj = blockIdx.y, b = blockIdx.z;
    const float *W, *bias;
    if (proj == 0) { W = w_theta; bias = b_theta; }
    else if (proj == 1) { W = w_phi; bias = b_phi; }
    else { W = w_g; bias = b_g; }
    float scl = (proj == 0) ? LOG2E : 1.0f;
    int t = threadIdx.x, lane = t & 63, wave = t >> 6;
    int l16 = lane & 15, l4 = lane >> 4;

    f32x4 acc[2][8];
#pragma unroll
    for (int mf = 0; mf < 2; mf++)
#pragma unroll
        for (int nf = 0; nf < 8; nf++)
#pragma unroll
            for (int e = 0; e < 4; e++) acc[mf][nf][e] = 0.f;

    const unsigned short* xtp = xT + (size_t)b * NN * CC;
    for (int kc = 0; kc < 4; kc++) {
        int c0k = kc * 64;
        __syncthreads();
#pragma unroll
        for (int i = 0; i < 4; i++) {  // stage [128 n][64 c]
            int idx = t + 256 * i;
            int n = idx >> 3, cc = (idx & 7) * 8;
            *(short8*)&xs[n][cc] = *(const short8*)(xtp + (size_t)(nb + n) * CC + c0k + cc);
        }
        __syncthreads();
        short8 af[2][2];
#pragma unroll
        for (int mf = 0; mf < 2; mf++)
#pragma unroll
            for (int ic = 0; ic < 2; ic++) {
                int d = wave * 32 + mf * 16 + l16;
                const float* wp = W + d * CC + c0k + ic * 32 + l4 * 8;
                af[mf][ic] = pack8(*(const float4*)wp, *(const float4*)(wp + 4));
            }
#pragma unroll
        for (int nf = 0; nf < 8; nf++)
#pragma unroll
            for (int ic = 0; ic < 2; ic++) {
                short8 bfr = *(const short8*)&xs[nf * 16 + l16][ic * 32 + l4 * 8];
                acc[0][nf] = __builtin_amdgcn_mfma_f32_16x16x32_bf16(af[0][ic], bfr, acc[0][nf], 0, 0, 0);
                acc[1][nf] = __builtin_amdgcn_mfma_f32_16x16x32_bf16(af[1][ic], bfr, acc[1][nf], 0, 0, 0);
            }
    }
    // acc C-layout: col(l16) = n-within-frag, row(l4*4+r) = d-within-frag
    __syncthreads();  // xs done; rp reuse safe
    if (proj < 2) {
        unsigned short* outp = (proj == 0 ? qws : kws) + (size_t)b * NN * DD;
#pragma unroll
        for (int mf = 0; mf < 2; mf++) {
            int d0 = wave * 32 + mf * 16 + l4 * 4;
            float bb[4];
#pragma unroll
            for (int r = 0; r < 4; r++) bb[r] = bias[d0 + r];
#pragma unroll
            for (int nf = 0; nf < 8; nf++) {
                short4v pk;
#pragma unroll
                for (int r = 0; r < 4; r++) pk[r] = (short)f2bf((acc[mf][nf][r] + bb[r]) * scl);
                *(short4v*)&rp[nf * 16 + l16][d0] = pk;
            }
        }
        __syncthreads();
#pragma unroll
        for (int i = 0; i < 8; i++) {
            int idx = t + 256 * i;
            int n = idx >> 4, dd = (idx & 15) * 8;
            *(short8*)(outp + (size_t)(nb + n) * DD + dd) = *(const short8*)&rp[n][dd];
        }
    } else {
#pragma unroll
        for (int mf = 0; mf < 2; mf++) {
            int drow = wave * 32 + mf * 16 + l4 * 4;
            float bb[4];
#pragma unroll
            for (int r = 0; r < 4; r++) bb[r] = bias[drow + r];
#pragma unroll
            for (int nf = 0; nf < 8; nf++)
#pragma unroll
                for (int r = 0; r < 4; r++)
                    rp[drow + r][nf * 16 + l16] = f2bf(acc[mf][nf][r] + bb[r]);
        }
        __syncthreads();
        unsigned short* outp = vtws + (size_t)b * DD * NN;
#pragma unroll
        for (int i = 0; i < 8; i++) {
            int idx = t + 256 * i;
            int d = idx >> 4, n0 = (idx & 15) * 8;
            *(short8*)(outp + (size_t)d * NN + nb + n0) = *(const short8*)&rp[d][n0];
        }
    }
}

// ---------------- kernel 3: flash attention — 2-wave blocks, T15 pipelined (macro form) ----
// grid 1024 = 8 b x 2 ks x 64 q-tiles (4 blocks/CU). Wave owns 32 q-rows. KVBLK=32, NIT=64.
// Swapped QK^T (S^T = mfma(K,Q)); softmax lane-local; PV A-frags in-register via
// cvt_pk_bf16 + permlane32_swap (T12). T15: iter t interleaves softmax(t)+PV(t) with
// QK^T(t+1). ALL state in statically-named registers (r3's lambda-by-reference spilled:
// WRITE_SIZE 420MB scratch signature). Single S-accumulator chain (full-rate acc fwd).
// LDS: dbuf K (32x256B, swz ^(row&7)) + V (128x64B, swz ^((row^row>>2)&3)); parities
// passed as macro literals. Two barriers/iter.
#define KFRAG(BUF, KC) \
    (*(const short8*)((BUF) + l31 * 256 + (((((KC) << 1) | hi) ^ (l31 & 7)) << 4)))

#define QGROUP(SC, SN, KBN, G, P0, P1, P2, P3)                                        \
    P0 = __builtin_exp2f(SC[4 * (G) + 0]); lsum0 += P0;                               \
    P1 = __builtin_exp2f(SC[4 * (G) + 1]); lsum1 += P1;                               \
    P2 = __builtin_exp2f(SC[4 * (G) + 2]); lsum0 += P2;                               \
    P3 = __builtin_exp2f(SC[4 * (G) + 3]); lsum1 += P3;                               \
    SN = __builtin_amdgcn_mfma_f32_32x32x16_bf16(KFRAG(KBN, 2 * (G)), qreg[2 * (G)], SN, 0, 0, 0); \
    SN = __builtin_amdgcn_mfma_f32_32x32x16_bf16(KFRAG(KBN, 2 * (G) + 1), qreg[2 * (G) + 1], SN, 0, 0, 0);

#define PABUILD(PA, Pa, Pb, Pc, Pd, Pe, Pf_, Pg, Ph) {                                \
    unsigned x0 = cvtpk_bf16(Pa, Pb);                                                 \
    unsigned x1 = cvtpk_bf16(Pc, Pd);                                                 \
    unsigned y0 = cvtpk_bf16(Pe, Pf_);                                                \
    unsigned y1 = cvtpk_bf16(Pg, Ph);                                                 \
    pl32swap(x0, y0); pl32swap(x1, y1);                                               \
    PA[0] = x0; PA[1] = x1; PA[2] = y0; PA[3] = y1; }

#define PVSTEP(DF, PA0, PA1) {                                                        \
    int row_ = (DF) * 32 + l31;                                                       \
    int sw_ = (row_ ^ (row_ >> 2)) & 3;                                               \
    short8 vb0 = *(const short8*)(Vb + row_ * 64 + (((0 | hi) ^ sw_) << 4));          \
    short8 vb1 = *(const short8*)(Vb + row_ * 64 + (((2 | hi) ^ sw_) << 4));          \
    o[DF] = __builtin_amdgcn_mfma_f32_32x32x16_bf16(                                  \
        __builtin_bit_cast(short8, PA0), vb0, o[DF], 0, 0, 0);                        \
    o[DF] = __builtin_amdgcn_mfma_f32_32x32x16_bf16(                                  \
        __builtin_bit_cast(short8, PA1), vb1, o[DF], 0, 0, 0); }

// PAR = (ITC & 1) as a literal. KbN = K buffer of tile ITC+1; Vb = V of tile ITC;
// KbW/VbW = write dest for tile ITC+2 (overwrites tile ITC's buffers).
#define FLASH_BODY(ITC, PAR, SC, SN) {                                                \
    char* KbN = (char*)smem + ((PAR) ^ 1) * 8192;                                     \
    char* Vb  = (char*)smem + 16384 + (PAR) * 8192;                                   \
    char* KbW = (char*)smem + (PAR) * 8192;                                           \
    char* VbW = (char*)smem + 16384 + (PAR) * 8192;                                   \
    uint4 kr0, kr1, kr2, kr3, vr0, vr1, vr2, vr3;                                     \
    bool pf = ((ITC) + 2 < NIT);                                                      \
    if (pf) {                                                                         \
        int mb2 = kbase + ((ITC) + 2) * 32;                                           \
        int i0 = t, i1 = t + 128, i2 = t + 256, i3 = t + 384;                         \
        kr0 = *(const uint4*)(kp + (size_t)(mb2 + (i0 >> 4)) * DD + (i0 & 15) * 8);   \
        kr1 = *(const uint4*)(kp + (size_t)(mb2 + (i1 >> 4)) * DD + (i1 & 15) * 8);   \
        kr2 = *(const uint4*)(kp + (size_t)(mb2 + (i2 >> 4)) * DD + (i2 & 15) * 8);   \
        kr3 = *(const uint4*)(kp + (size_t)(mb2 + (i3 >> 4)) * DD + (i3 & 15) * 8);   \
        vr0 = *(const uint4*)(vp + (size_t)(i0 >> 2) * NN + mb2 + (i0 & 3) * 8);      \
        vr1 = *(const uint4*)(vp + (size_t)(i1 >> 2) * NN + mb2 + (i1 & 3) * 8);      \
        vr2 = *(const uint4*)(vp + (size_t)(i2 >> 2) * NN + mb2 + (i2 & 3) * 8);      \
        vr3 = *(const uint4*)(vp + (size_t)(i3 >> 2) * NN + mb2 + (i3 & 3) * 8);      \
    }                                                                                 \
    _Pragma("unroll") for (int e = 0; e < 16; e++) SN[e] = -MSHIFT;                   \
    float p0, p1, p2, p3, p4, p5, p6, p7, p8, p9, p10, p11, p12, p13, p14, p15;       \
    __builtin_amdgcn_s_setprio(1);                                                    \
    QGROUP(SC, SN, KbN, 0, p0, p1, p2, p3)                                            \
    QGROUP(SC, SN, KbN, 1, p4, p5, p6, p7)                                            \
    u32x4 paA; PABUILD(paA, p0, p1, p2, p3, p4, p5, p6, p7)                           \
    QGROUP(SC, SN, KbN, 2, p8, p9, p10, p11)                                          \
    QGROUP(SC, SN, KbN, 3, p12, p13, p14, p15)                                        \
    u32x4 paB; PABUILD(paB, p8, p9, p10, p11, p12, p13, p14, p15)                     \
    PVSTEP(0, paA, paB)                                                               \
    PVSTEP(1, paA, paB)                                                               \
    PVSTEP(2, paA, paB)                                                               \
    PVSTEP(3, paA, paB)                                                               \
    __builtin_amdgcn_s_setprio(0);                                                    \
    __syncthreads();                                                                  \
    if (pf) {                                                                         \
        int i0 = t, i1 = t + 128, i2 = t + 256, i3 = t + 384;                         \
        *(uint4*)(KbW + (i0 >> 4) * 256 + (((i0 & 15) ^ ((i0 >> 4) & 7)) << 4)) = kr0; \
        *(uint4*)(KbW + (i1 >> 4) * 256 + (((i1 & 15) ^ ((i1 >> 4) & 7)) << 4)) = kr1; \
        *(uint4*)(KbW + (i2 >> 4) * 256 + (((i2 & 15) ^ ((i2 >> 4) & 7)) << 4)) = kr2; \
        *(uint4*)(KbW + (i3 >> 4) * 256 + (((i3 & 15) ^ ((i3 >> 4) & 7)) << 4)) = kr3; \
        *(uint4*)(VbW + (i0 >> 2) * 64 + ((((i0 & 3) ^ (((i0 >> 2) ^ (i0 >> 4)) & 3)) << 4))) = vr0; \
        *(uint4*)(VbW + (i1 >> 2) * 64 + ((((i1 & 3) ^ (((i1 >> 2) ^ (i1 >> 4)) & 3)) << 4))) = vr1; \
        *(uint4*)(VbW + (i2 >> 2) * 64 + ((((i2 & 3) ^ (((i2 >> 2) ^ (i2 >> 4)) & 3)) << 4))) = vr2; \
        *(uint4*)(VbW + (i3 >> 2) * 64 + ((((i3 & 3) ^ (((i3 >> 2) ^ (i3 >> 4)) & 3)) << 4))) = vr3; \
    }                                                                                 \
    __syncthreads(); }

__global__ __launch_bounds__(128, 2) void k_flash(
        const unsigned short* __restrict__ q, const unsigned short* __restrict__ kk,
        const unsigned short* __restrict__ vt, unsigned short* __restrict__ opart,
        float* __restrict__ lsums) {
    __shared__ __align__(16) unsigned char smem[32768];
    // K[buf] at buf*8192 (32 rows x 256 B); V[buf] at 16384 + buf*8192 (128 rows x 64 B)

    int bid = blockIdx.x;
    int b   = bid & 7;           // batch -> XCD (round-robin dispatch): K/V L2-resident
    int rem = bid >> 3;
    int ks  = rem >> 6;
    int qt  = rem & 63;
    int qb  = qt * 64;

    int t = threadIdx.x, lane = t & 63, wave = t >> 6;
    int l31 = lane & 31, hi = lane >> 5;

    const unsigned short* qp = q  + (size_t)b * NN * DD;
    const unsigned short* kp = kk + (size_t)b * NN * DD;
    const unsigned short* vp = vt + (size_t)b * DD * NN;

    // Q fragments (B-operand of swapped QK^T): lane holds Q[qb+w*32+l31][kc*16+hi*8+e]
    short8 qreg[8];
    {
        int qrow = qb + wave * 32 + l31;
#pragma unroll
        for (int kc = 0; kc < 8; kc++)
            qreg[kc] = *(const short8*)(qp + (size_t)qrow * DD + kc * 16 + hi * 8);
    }

    f32x16 o[4];
#pragma unroll
    for (int df = 0; df < 4; df++)
#pragma unroll
        for (int e = 0; e < 16; e++) o[df][e] = 0.f;
    float lsum0 = 0.f, lsum1 = 0.f;

    int kbase = ks * (NN / 2);
    const int NIT = (NN / 2) / 32;  // 64

    // prologue: stage tiles 0 and 1 into buffers 0 and 1
#pragma unroll
    for (int pt = 0; pt < 2; pt++) {
        uint4 k0[4], v0[4];
        int mb = kbase + pt * 32;
#pragma unroll
        for (int i = 0; i < 4; i++) {
            int idx = t + 128 * i;  // 0..511
            k0[i] = *(const uint4*)(kp + (size_t)(mb + (idx >> 4)) * DD + (idx & 15) * 8);
            v0[i] = *(const uint4*)(vp + (size_t)(idx >> 2) * NN + mb + (idx & 3) * 8);
        }
        char* Kb = (char*)smem + pt * 8192;
        char* Vb = (char*)smem + 16384 + pt * 8192;
#pragma unroll
        for (int i = 0; i < 4; i++) {
            int idx = t + 128 * i;
            int rk = idx >> 4, ck = idx & 15;
            *(uint4*)(Kb + rk * 256 + ((ck ^ (rk & 7)) << 4)) = k0[i];
            int rv = idx >> 2, cv = idx & 3;
            *(uint4*)(Vb + rv * 64 + ((cv ^ ((rv ^ (rv >> 2)) & 3)) << 4)) = v0[i];
        }
    }
    __syncthreads();

    // QK^T(0) from buffer 0: single chained accumulator (full-rate C-forwarding)
    f32x16 s0, s1;
#pragma unroll
    for (int e = 0; e < 16; e++) s0[e] = -MSHIFT;
    {
        char* Kb0 = (char*)smem;
        __builtin_amdgcn_s_setprio(1);
#pragma unroll
        for (int kc = 0; kc < 8; kc++)
            s0 = __builtin_amdgcn_mfma_f32_32x32x16_bf16(KFRAG(Kb0, kc), qreg[kc], s0, 0, 0, 0);
        __builtin_amdgcn_s_setprio(0);
    }

    for (int it = 0; it < NIT; it += 2) {
        FLASH_BODY(it, 0, s0, s1)
        FLASH_BODY(it + 1, 1, s1, s0)
    }

    // ---- epilogue: row-sums + staged coalesced O-partial store ----
    {
        float lsum = lsum0 + lsum1;
        float tot = lsum + __shfl_xor(lsum, 32);
        if (lane < 32)
            lsums[((size_t)ks * BB + b) * NN + qb + wave * 32 + l31] = tot;
    }
    unsigned short (*Ox)[136] = (unsigned short (*)[136])smem;  // 64 x 136 (17408 B)
#pragma unroll
    for (int df = 0; df < 4; df++)
#pragma unroll
        for (int r = 0; r < 16; r++) {
            int qr = (r & 3) + 8 * (r >> 2) + 4 * hi;
            Ox[wave * 32 + qr][df * 32 + l31] = f2bf(o[df][r]);
        }
    __syncthreads();
    unsigned short* op = opart + (((size_t)ks * BB + b) * NN + qb) * DD;
#pragma unroll
    for (int i = 0; i < 8; i++) {
        int idx = t + 128 * i;  // 0..1023
        int nr = idx >> 4, c0 = (idx & 15) * 8;
        *(short8*)(op + (size_t)nr * DD + c0) = *(const short8*)&Ox[nr][c0];
    }
}

// ---------------- kernel 4: combine partials + out = w_mask . y^T + b_mask + x ----------------
// grid (NN/64, 2, BB), block 256; cs = blockIdx.y picks c-range cs*128..+128
__global__ __launch_bounds__(256) void k_maskout(
        const unsigned short* __restrict__ opart, const float* __restrict__ lsums,
        const float* __restrict__ w_mask, const float* __restrict__ b_mask,
        const float* __restrict__ x, float* __restrict__ out) {
    __shared__ __align__(16) unsigned short Ys[64][136];
    __shared__ float invl[64];
    int nb = blockIdx.x * 64, cs = blockIdx.y, b = blockIdx.z;
    int t = threadIdx.x, lane = t & 63, wave = t >> 6;
    int l16 = lane & 15, l4 = lane >> 4;

    const unsigned short* o0 = opart + ((size_t)b * NN + nb) * DD;
    const unsigned short* o1 = opart + (((size_t)BB + b) * NN + nb) * DD;
    if (t < 64) {
        float ls0 = lsums[(size_t)b * NN + nb + t];
        float ls1 = lsums[((size_t)BB + b) * NN + nb + t];
        invl[t] = 1.0f / (ls0 + ls1);
    }
    __syncthreads();
#pragma unroll
    for (int i = 0; i < 4; i++) {  // combine the 2 key-split partials while staging y
        int idx = t + 256 * i;
        int nr = idx >> 4, d0 = (idx & 15) * 8;
        short8 a = *(const short8*)(o0 + (size_t)nr * DD + d0);
        short8 c = *(const short8*)(o1 + (size_t)nr * DD + d0);
        float inv = invl[nr];
        short8 yv;
#pragma unroll
        for (int j = 0; j < 8; j++)
            yv[j] = (short)f2bf((bf2f((unsigned short)a[j]) + bf2f((unsigned short)c[j])) * inv);
        *(short8*)&Ys[nr][d0] = yv;
    }
    __syncthreads();

    f32x4 acc[2][4];
#pragma unroll
    for (int mf = 0; mf < 2; mf++)
#pragma unroll
        for (int nf = 0; nf < 4; nf++)
#pragma unroll
            for (int e = 0; e < 4; e++) acc[mf][nf][e] = 0.f;

#pragma unroll
    for (int kc = 0; kc < 4; kc++) {
        int d0 = kc * 32 + l4 * 8;
        short8 af[2];
#pragma unroll
        for (int mf = 0; mf < 2; mf++) {
            int c = cs * 128 + wave * 32 + mf * 16 + l16;
            const float* wp = w_mask + c * DD + d0;
            af[mf] = pack8(*(const float4*)wp, *(const float4*)(wp + 4));
        }
#pragma unroll
        for (int nf = 0; nf < 4; nf++) {
            short8 bfr = *(const short8*)&Ys[nf * 16 + l16][d0];
#pragma unroll
            for (int mf = 0; mf < 2; mf++)
                acc[mf][nf] = __builtin_amdgcn_mfma_f32_16x16x32_bf16(af[mf], bfr, acc[mf][nf], 0, 0, 0);
        }
    }

    const float* xp = x + (size_t)b * CC * NN;
    float* op = out + (size_t)b * CC * NN;
#pragma unroll
    for (int mf = 0; mf < 2; mf++) {
        int c0 = cs * 128 + wave * 32 + mf * 16 + l4 * 4;
        float bb[4];
#pragma unroll
        for (int r = 0; r < 4; r++) bb[r] = b_mask[c0 + r];
#pragma unroll
        for (int r = 0; r < 4; r++) {
            size_t rowoff = (size_t)(c0 + r) * NN;
#pragma unroll
            for (int nf = 0; nf < 4; nf++) {
                int n = nb + nf * 16 + l16;
                op[rowoff + n] = acc[mf][nf][r] + bb[r] + xp[rowoff + n];
            }
        }
    }
}

extern "C" void kernel_launch(void* const* d_in, const int* in_sizes, int n_in,
                              void* d_out, int out_size, void* d_ws, size_t ws_size,
                              hipStream_t stream) {
    const float* x       = (const float*)d_in[0];
    const float* w_phi   = (const float*)d_in[1];
    const float* b_phi   = (const float*)d_in[2];
    const float* w_theta = (const float*)d_in[3];
    const float* b_theta = (const float*)d_in[4];
    const float* w_g     = (const float*)d_in[5];
    const float* b_g     = (const float*)d_in[6];
    const float* w_mask  = (const float*)d_in[7];
    const float* b_mask  = (const float*)d_in[8];
    float* out = (float*)d_out;

    // ws (48 MiB): [0,16M): xT (dead after k_proj) -> reused as Opart (2*8*4096*128 bf16 = 16 MiB)
    //              [16,24M): Q | [24,32M): K | [32,40M): Vt | [40M+): lsums (2*8*4096 fp32 = 256 KiB)
    char* ws = (char*)d_ws;
    unsigned short* xT    = (unsigned short*)(ws);
    unsigned short* opart = (unsigned short*)(ws);  // overlays xT after proj
    unsigned short* qw    = (unsigned short*)(ws + ((size_t)16 << 20));
    unsigned short* kw    = (unsigned short*)(ws + ((size_t)24 << 20));
    unsigned short* vtw   = (unsigned short*)(ws + ((size_t)32 << 20));
    float*          lsums = (float*)(ws + ((size_t)40 << 20));

    k_transpose_x<<<dim3(NN / 64, CC / 64, BB), 256, 0, stream>>>(x, xT);
    k_proj<<<dim3(NN / 128, 3, BB), 256, 0, stream>>>(xT, w_phi, b_phi, w_theta, b_theta,
                                                      w_g, b_g, qw, kw, vtw);
    k_flash<<<dim3(1024, 1, 1), 128, 0, stream>>>(qw, kw, vtw, opart, lsums);
    k_maskout<<<dim3(NN / 64, 2, BB), 256, 0, stream>>>(opart, lsums, w_mask, b_mask, x, out);
}

// Round 5
// 233.411 us; speedup vs baseline: 1.8279x; 1.2649x over previous
//
#include <hip/hip_runtime.h>

#define BB 8
#define CC 256
#define DD 128
#define NN 4096

#define LOG2E 1.44269504f
#define MSHIFT 32.0f  // fixed softmax shift (base-2 domain); |S*log2e| << 32 always

typedef __attribute__((ext_vector_type(8))) short short8;
typedef __attribute__((ext_vector_type(4))) short short4v;
typedef __attribute__((ext_vector_type(4))) float f32x4;
typedef __attribute__((ext_vector_type(16))) float f32x16;
typedef __attribute__((ext_vector_type(4))) unsigned int u32x4;

static __device__ __forceinline__ unsigned short f2bf(float f) {
    unsigned u = __builtin_bit_cast(unsigned, f);
    u += 0x7FFFu + ((u >> 16) & 1u);
    return (unsigned short)(u >> 16);
}
static __device__ __forceinline__ float bf2f(unsigned short h) {
    unsigned u = ((unsigned)h) << 16;
    return __builtin_bit_cast(float, u);
}
static __device__ __forceinline__ short8 pack8(float4 a, float4 b) {
    short8 r;
    r[0] = (short)f2bf(a.x); r[1] = (short)f2bf(a.y);
    r[2] = (short)f2bf(a.z); r[3] = (short)f2bf(a.w);
    r[4] = (short)f2bf(b.x); r[5] = (short)f2bf(b.y);
    r[6] = (short)f2bf(b.z); r[7] = (short)f2bf(b.w);
    return r;
}
// packed f32x2 -> bf16x2 (RNE); element 0 in low 16 bits
static __device__ __forceinline__ unsigned cvtpk_bf16(float lo, float hi) {
    unsigned r;
    asm("v_cvt_pk_bf16_f32 %0, %1, %2" : "=v"(r) : "v"(lo), "v"(hi));
    return r;
}
// swap upper 32 lanes of a with lower 32 lanes of b (T12 primitive)
static __device__ __forceinline__ void pl32swap(unsigned &a, unsigned &b) {
#if __has_builtin(__builtin_amdgcn_permlane32_swap)
    auto r = __builtin_amdgcn_permlane32_swap((int)a, (int)b, false, false);
    a = (unsigned)r[0]; b = (unsigned)r[1];
#else
    asm("v_permlane32_swap_b32 %0, %1" : "+v"(a), "+v"(b));
#endif
}

// ---------------- kernel 2: projections (transpose FUSED; x read directly) ----------------
// proj 0: theta*log2e -> Q[n][d]; proj 1: phi -> K[n][d]; proj 2: g -> Vt[d][n]
// grid (NN/128, 3, BB), block 256 (4 waves; wave owns d-range wave*32..+32).
// Staging: reads x fp32 [c][n] (8 float4/thread), converts + transposes into LDS
// xs[n][col] with column swizzle col = (c + 16*(n>>5)) & 63 -> write phase is 2-way
// bank-aliased (free), MFMA-read phase unchanged 2-way. Eliminates the xT kernel.
__global__ __launch_bounds__(256) void k_proj(
        const float* __restrict__ x,
        const float* __restrict__ w_phi, const float* __restrict__ b_phi,
        const float* __restrict__ w_theta, const float* __restrict__ b_theta,
        const float* __restrict__ w_g, const float* __restrict__ b_g,
        unsigned short* __restrict__ qws, unsigned short* __restrict__ kws,
        unsigned short* __restrict__ vtws) {
    __shared__ __align__(16) unsigned short xs[128][72];     // staged x^T chunk [n][64c swz]
    __shared__ __align__(16) unsigned short rp[128][136];    // repack buffer
    int nb = blockIdx.x * 128, proj = blockIdx.y, b = blockIdx.z;
    const float *W, *bias;
    if (proj == 0) { W = w_theta; bias = b_theta; }
    else if (proj == 1) { W = w_phi; bias = b_phi; }
    else { W = w_g; bias = b_g; }
    float scl = (proj == 0) ? LOG2E : 1.0f;
    int t = threadIdx.x, lane = t & 63, wave = t >> 6;
    int l16 = lane & 15, l4 = lane >> 4;

    f32x4 acc[2][8];
#pragma unroll
    for (int mf = 0; mf < 2; mf++)
#pragma unroll
        for (int nf = 0; nf < 8; nf++)
#pragma unroll
            for (int e = 0; e < 4; e++) acc[mf][nf][e] = 0.f;

    const float* xpb = x + (size_t)b * CC * NN;  // [c][n]
    int cl = t >> 2;               // 0..63: c within 64-chunk
    int gq = t & 3;                // n-group (32 n each)
    int n0 = gq * 32;
    int wcol = (cl + 16 * gq) & 63;  // swizzled write column

    for (int kc = 0; kc < 4; kc++) {
        int c0k = kc * 64;
        __syncthreads();
        {   // stage: read 32 consecutive floats of row (c0k+cl), transpose into xs
            const float* src = xpb + (size_t)(c0k + cl) * NN + nb + n0;
            float4 xv[8];
#pragma unroll
            for (int j = 0; j < 8; j++) xv[j] = *(const float4*)(src + 4 * j);
#pragma unroll
            for (int j = 0; j < 8; j++) {
                xs[n0 + 4 * j + 0][wcol] = f2bf(xv[j].x);
                xs[n0 + 4 * j + 1][wcol] = f2bf(xv[j].y);
                xs[n0 + 4 * j + 2][wcol] = f2bf(xv[j].z);
                xs[n0 + 4 * j + 3][wcol] = f2bf(xv[j].w);
            }
        }
        __syncthreads();
        short8 af[2][2];
#pragma unroll
        for (int mf = 0; mf < 2; mf++)
#pragma unroll
            for (int ic = 0; ic < 2; ic++) {
                int d = wave * 32 + mf * 16 + l16;
                const float* wp = W + d * CC + c0k + ic * 32 + l4 * 8;
                af[mf][ic] = pack8(*(const float4*)wp, *(const float4*)(wp + 4));
            }
#pragma unroll
        for (int nf = 0; nf < 8; nf++)
#pragma unroll
            for (int ic = 0; ic < 2; ic++) {
                int rcol = (ic * 32 + l4 * 8 + 16 * (nf >> 1)) & 63;
                short8 bfr = *(const short8*)&xs[nf * 16 + l16][rcol];
                acc[0][nf] = __builtin_amdgcn_mfma_f32_16x16x32_bf16(af[0][ic], bfr, acc[0][nf], 0, 0, 0);
                acc[1][nf] = __builtin_amdgcn_mfma_f32_16x16x32_bf16(af[1][ic], bfr, acc[1][nf], 0, 0, 0);
            }
    }
    // acc C-layout: col(l16) = n-within-frag, row(l4*4+r) = d-within-frag
    __syncthreads();  // xs done; rp reuse safe
    if (proj < 2) {
        unsigned short* outp = (proj == 0 ? qws : kws) + (size_t)b * NN * DD;
#pragma unroll
        for (int mf = 0; mf < 2; mf++) {
            int d0 = wave * 32 + mf * 16 + l4 * 4;
            float bb[4];
#pragma unroll
            for (int r = 0; r < 4; r++) bb[r] = bias[d0 + r];
#pragma unroll
            for (int nf = 0; nf < 8; nf++) {
                short4v pk;
#pragma unroll
                for (int r = 0; r < 4; r++) pk[r] = (short)f2bf((acc[mf][nf][r] + bb[r]) * scl);
                *(short4v*)&rp[nf * 16 + l16][d0] = pk;
            }
        }
        __syncthreads();
#pragma unroll
        for (int i = 0; i < 8; i++) {
            int idx = t + 256 * i;
            int n = idx >> 4, dd = (idx & 15) * 8;
            *(short8*)(outp + (size_t)(nb + n) * DD + dd) = *(const short8*)&rp[n][dd];
        }
    } else {
#pragma unroll
        for (int mf = 0; mf < 2; mf++) {
            int drow = wave * 32 + mf * 16 + l4 * 4;
            float bb[4];
#pragma unroll
            for (int r = 0; r < 4; r++) bb[r] = bias[drow + r];
#pragma unroll
            for (int nf = 0; nf < 8; nf++)
#pragma unroll
                for (int r = 0; r < 4; r++)
                    rp[drow + r][nf * 16 + l16] = f2bf(acc[mf][nf][r] + bb[r]);
        }
        __syncthreads();
        unsigned short* outp = vtws + (size_t)b * DD * NN;
#pragma unroll
        for (int i = 0; i < 8; i++) {
            int idx = t + 256 * i;
            int d = idx >> 4, n0s = (idx & 15) * 8;
            *(short8*)(outp + (size_t)d * NN + nb + n0s) = *(const short8*)&rp[d][n0s];
        }
    }
}

// ---------------- kernel 3: flash attention — 2-wave blocks, 32x32 MFMA, in-reg softmax ----
// (round-2 verified version: 110 us, MfmaUtil 27, no spill)
// grid 1024 = 8 b x 2 ks x 64 q-tiles (4 independent blocks/CU for latency hiding).
// Wave w owns 32 q-rows (qb + w*32 + l31). KVBLK = 32 keys/iter, NIT = 64.
// Swapped QK^T: S^T = mfma_32x32x16(K, Q) -> lane holds S[key][q=l31]; softmax lane-local;
// PV A-frags built in-register via cvt_pk_bf16 + permlane32_swap (T12).
// LDS: double-buffered K (32x256B, swz ^(row&7)) + V (128x64B, swz ^((row^row>>2)&3));
// ONE barrier per iter: issue loads(t+1) -> compute(t) -> write buf^1 -> barrier.
__global__ __launch_bounds__(128, 2) void k_flash(
        const unsigned short* __restrict__ q, const unsigned short* __restrict__ kk,
        const unsigned short* __restrict__ vt, unsigned short* __restrict__ opart,
        float* __restrict__ lsums) {
    __shared__ __align__(16) unsigned char smem[32768];
    // K[buf] at buf*8192 (32 rows x 256 B); V[buf] at 16384 + buf*8192 (128 rows x 64 B)

    int bid = blockIdx.x;
    int b   = bid & 7;           // batch -> XCD (round-robin dispatch): K/V L2-resident
    int rem = bid >> 3;
    int ks  = rem >> 6;
    int qt  = rem & 63;
    int qb  = qt * 64;

    int t = threadIdx.x, lane = t & 63, wave = t >> 6;
    int l31 = lane & 31, hi = lane >> 5;

    const unsigned short* qp = q  + (size_t)b * NN * DD;
    const unsigned short* kp = kk + (size_t)b * NN * DD;
    const unsigned short* vp = vt + (size_t)b * DD * NN;

    // Q fragments (B-operand of swapped QK^T): lane holds Q[qb+w*32+l31][kc*16+hi*8+e]
    short8 qreg[8];
    {
        int qrow = qb + wave * 32 + l31;
#pragma unroll
        for (int kc = 0; kc < 8; kc++)
            qreg[kc] = *(const short8*)(qp + (size_t)qrow * DD + kc * 16 + hi * 8);
    }

    f32x16 o[4];
#pragma unroll
    for (int df = 0; df < 4; df++)
#pragma unroll
        for (int e = 0; e < 16; e++) o[df][e] = 0.f;
    float lsum0 = 0.f, lsum1 = 0.f;

    int kbase = ks * (NN / 2);
    const int NIT = (NN / 2) / 32;  // 64

    // prologue: stage tile 0 into buffer 0
    {
        uint4 k0[4], v0[4];
#pragma unroll
        for (int i = 0; i < 4; i++) {
            int idx = t + 128 * i;  // 0..511
            k0[i] = *(const uint4*)(kp + (size_t)(kbase + (idx >> 4)) * DD + (idx & 15) * 8);
            v0[i] = *(const uint4*)(vp + (size_t)(idx >> 2) * NN + kbase + (idx & 3) * 8);
        }
#pragma unroll
        for (int i = 0; i < 4; i++) {
            int idx = t + 128 * i;
            int rk = idx >> 4, ck = idx & 15;
            *(uint4*)((char*)smem + rk * 256 + ((ck ^ (rk & 7)) << 4)) = k0[i];
            int rv = idx >> 2, cv = idx & 3;
            *(uint4*)((char*)smem + 16384 + rv * 64 + ((cv ^ ((rv ^ (rv >> 2)) & 3)) << 4)) = v0[i];
        }
    }
    __syncthreads();

    for (int it = 0; it < NIT; ++it) {
        char* Kb  = (char*)smem + (it & 1) * 8192;
        char* Vb  = (char*)smem + 16384 + (it & 1) * 8192;
        char* Kb2 = (char*)smem + ((it & 1) ^ 1) * 8192;
        char* Vb2 = (char*)smem + 16384 + (((it & 1) ^ 1)) * 8192;

        // T14: issue next tile's global loads; latency hides under the 16 MFMAs below
        uint4 kreg[4], vreg[4];
        bool pf = (it + 1 < NIT);
        if (pf) {
            int mb2 = kbase + (it + 1) * 32;
#pragma unroll
            for (int i = 0; i < 4; i++) {
                int idx = t + 128 * i;
                kreg[i] = *(const uint4*)(kp + (size_t)(mb2 + (idx >> 4)) * DD + (idx & 15) * 8);
                vreg[i] = *(const uint4*)(vp + (size_t)(idx >> 2) * NN + mb2 + (idx & 3) * 8);
            }
        }

        // S^T = K . Q^T - 32 (two interleaved accumulators -> MFMA dep-distance 2)
        f32x16 sA, sB;
#pragma unroll
        for (int e = 0; e < 16; e++) { sA[e] = -MSHIFT; sB[e] = 0.f; }
        __builtin_amdgcn_s_setprio(1);
#pragma unroll
        for (int kc = 0; kc < 8; kc += 2) {
            short8 a0 = *(const short8*)(Kb + l31 * 256 + ((((kc << 1) | hi) ^ (l31 & 7)) << 4));
            short8 a1 = *(const short8*)(Kb + l31 * 256 + (((((kc + 1) << 1) | hi) ^ (l31 & 7)) << 4));
            sA = __builtin_amdgcn_mfma_f32_32x32x16_bf16(a0, qreg[kc], sA, 0, 0, 0);
            sB = __builtin_amdgcn_mfma_f32_32x32x16_bf16(a1, qreg[kc + 1], sB, 0, 0, 0);
        }
        __builtin_amdgcn_s_setprio(0);

        // p = exp2(s'); lane-local row partials; PV A-frags in-register (T12)
        u32x4 pa[2];
        {
            float p[16];
#pragma unroll
            for (int r = 0; r < 16; r++) {
                p[r] = __builtin_exp2f(sA[r] + sB[r]);
                if (r & 1) lsum1 += p[r]; else lsum0 += p[r];
            }
#pragma unroll
            for (int h = 0; h < 2; h++) {
                unsigned a0 = cvtpk_bf16(p[8 * h + 0], p[8 * h + 1]);
                unsigned a1 = cvtpk_bf16(p[8 * h + 2], p[8 * h + 3]);
                unsigned b0 = cvtpk_bf16(p[8 * h + 4], p[8 * h + 5]);
                unsigned b1 = cvtpk_bf16(p[8 * h + 6], p[8 * h + 7]);
                pl32swap(a0, b0);
                pl32swap(a1, b1);
                u32x4 v; v[0] = a0; v[1] = a1; v[2] = b0; v[3] = b1;
                pa[h] = v;
            }
        }

        // O += P V  (V^T stored -> B-frag is a direct contiguous ds_read_b128)
        __builtin_amdgcn_s_setprio(1);
#pragma unroll
        for (int df = 0; df < 4; df++) {
            int row = df * 32 + l31;
            int sw = (row ^ (row >> 2)) & 3;
#pragma unroll
            for (int c = 0; c < 2; c++) {
                short8 vb = *(const short8*)(Vb + row * 64 + ((((c << 1) | hi) ^ sw) << 4));
                o[df] = __builtin_amdgcn_mfma_f32_32x32x16_bf16(
                    __builtin_bit_cast(short8, pa[c]), vb, o[df], 0, 0, 0);
            }
        }
        __builtin_amdgcn_s_setprio(0);

        // write prefetched tile to the other buffer; compiler inserts the vmcnt waits
        if (pf) {
#pragma unroll
            for (int i = 0; i < 4; i++) {
                int idx = t + 128 * i;
                int rk = idx >> 4, ck = idx & 15;
                *(uint4*)(Kb2 + rk * 256 + ((ck ^ (rk & 7)) << 4)) = kreg[i];
                int rv = idx >> 2, cv = idx & 3;
                *(uint4*)(Vb2 + rv * 64 + ((cv ^ ((rv ^ (rv >> 2)) & 3)) << 4)) = vreg[i];
            }
        }
        __syncthreads();  // buf[cur] free for iter t+1's writes; buf[cur^1] ready
    }

    // ---- epilogue: row-sums + staged coalesced O-partial store ----
    {
        float lsum = lsum0 + lsum1;
        float tot = lsum + __shfl_xor(lsum, 32);
        if (lane < 32)
            lsums[((size_t)ks * BB + b) * NN + qb + wave * 32 + l31] = tot;
    }
    unsigned short (*Ox)[136] = (unsigned short (*)[136])smem;  // 64 x 136 (17408 B)
#pragma unroll
    for (int df = 0; df < 4; df++)
#pragma unroll
        for (int r = 0; r < 16; r++) {
            int qr = (r & 3) + 8 * (r >> 2) + 4 * hi;
            Ox[wave * 32 + qr][df * 32 + l31] = f2bf(o[df][r]);
        }
    __syncthreads();
    unsigned short* op = opart + (((size_t)ks * BB + b) * NN + qb) * DD;
#pragma unroll
    for (int i = 0; i < 8; i++) {
        int idx = t + 128 * i;  // 0..1023
        int nr = idx >> 4, c0 = (idx & 15) * 8;
        *(short8*)(op + (size_t)nr * DD + c0) = *(const short8*)&Ox[nr][c0];
    }
}

// ---------------- kernel 4: combine partials + out = w_mask . y^T + b_mask + x ----------------
// grid (NN/64, 2, BB), block 256; cs = blockIdx.y picks c-range cs*128..+128.
// v2: epilogue stages acc+bias into LDS fp32 [128][68] then does fully vectorized
// float4 {LDS read, x load, out store} (256B segments) instead of 32 scalar ops/thread.
__global__ __launch_bounds__(256) void k_maskout(
        const unsigned short* __restrict__ opart, const float* __restrict__ lsums,
        const float* __restrict__ w_mask, const float* __restrict__ b_mask,
        const float* __restrict__ x, float* __restrict__ out) {
    __shared__ __align__(16) unsigned char pool[35072];
    unsigned short (*Ys)[136] = (unsigned short (*)[136])pool;  // 64x136x2B = 17408
    float (*Os)[68] = (float (*)[68])pool;                       // 128x68x4B = 34816 (overlays Ys)
    float* invl = (float*)(pool + 34816);                        // 256 B
    int nb = blockIdx.x * 64, cs = blockIdx.y, b = blockIdx.z;
    int t = threadIdx.x, lane = t & 63, wave = t >> 6;
    int l16 = lane & 15, l4 = lane >> 4;

    const unsigned short* o0 = opart + ((size_t)b * NN + nb) * DD;
    const unsigned short* o1 = opart + (((size_t)BB + b) * NN + nb) * DD;
    if (t < 64) {
        float ls0 = lsums[(size_t)b * NN + nb + t];
        float ls1 = lsums[((size_t)BB + b) * NN + nb + t];
        invl[t] = 1.0f / (ls0 + ls1);
    }
    __syncthreads();
#pragma unroll
    for (int i = 0; i < 4; i++) {  // combine the 2 key-split partials while staging y
        int idx = t + 256 * i;
        int nr = idx >> 4, d0 = (idx & 15) * 8;
        short8 a = *(const short8*)(o0 + (size_t)nr * DD + d0);
        short8 c = *(const short8*)(o1 + (size_t)nr * DD + d0);
        float inv = invl[nr];
        short8 yv;
#pragma unroll
        for (int j = 0; j < 8; j++)
            yv[j] = (short)f2bf((bf2f((unsigned short)a[j]) + bf2f((unsigned short)c[j])) * inv);
        *(short8*)&Ys[nr][d0] = yv;
    }
    __syncthreads();

    f32x4 acc[2][4];
#pragma unroll
    for (int mf = 0; mf < 2; mf++)
#pragma unroll
        for (int nf = 0; nf < 4; nf++)
#pragma unroll
            for (int e = 0; e < 4; e++) acc[mf][nf][e] = 0.f;

#pragma unroll
    for (int kc = 0; kc < 4; kc++) {
        int d0 = kc * 32 + l4 * 8;
        short8 af[2];
#pragma unroll
        for (int mf = 0; mf < 2; mf++) {
            int c = cs * 128 + wave * 32 + mf * 16 + l16;
            const float* wp = w_mask + c * DD + d0;
            af[mf] = pack8(*(const float4*)wp, *(const float4*)(wp + 4));
        }
#pragma unroll
        for (int nf = 0; nf < 4; nf++) {
            short8 bfr = *(const short8*)&Ys[nf * 16 + l16][d0];
#pragma unroll
            for (int mf = 0; mf < 2; mf++)
                acc[mf][nf] = __builtin_amdgcn_mfma_f32_16x16x32_bf16(af[mf], bfr, acc[mf][nf], 0, 0, 0);
        }
    }
    __syncthreads();  // all Ys reads done; Os overlays Ys

    // stage acc + bias into Os[128][68] fp32 (writes 2-way bank-aliased)
#pragma unroll
    for (int mf = 0; mf < 2; mf++) {
        int c0 = wave * 32 + mf * 16 + l4 * 4;  // local c 0..127
        float bb[4];
#pragma unroll
        for (int r = 0; r < 4; r++) bb[r] = b_mask[cs * 128 + c0 + r];
#pragma unroll
        for (int r = 0; r < 4; r++)
#pragma unroll
            for (int nf = 0; nf < 4; nf++)
                Os[c0 + r][nf * 16 + l16] = acc[mf][nf][r] + bb[r];
    }
    __syncthreads();

    // vectorized epilogue: out = Os + x (float4; 256B contiguous per c-row)
    const float* xp = x + (size_t)b * CC * NN + (size_t)cs * 128 * NN + nb;
    float* op = out + (size_t)b * CC * NN + (size_t)cs * 128 * NN + nb;
#pragma unroll
    for (int i = 0; i < 8; i++) {
        int idx = t + 256 * i;        // 0..2047
        int c = idx >> 4, nq = (idx & 15) * 4;
        float4 osv = *(const float4*)&Os[c][nq];
        float4 xv = *(const float4*)(xp + (size_t)c * NN + nq);
        float4 ov;
        ov.x = osv.x + xv.x; ov.y = osv.y + xv.y;
        ov.z = osv.z + xv.z; ov.w = osv.w + xv.w;
        *(float4*)(op + (size_t)c * NN + nq) = ov;
    }
}

extern "C" void kernel_launch(void* const* d_in, const int* in_sizes, int n_in,
                              void* d_out, int out_size, void* d_ws, size_t ws_size,
                              hipStream_t stream) {
    const float* x       = (const float*)d_in[0];
    const float* w_phi   = (const float*)d_in[1];
    const float* b_phi   = (const float*)d_in[2];
    const float* w_theta = (const float*)d_in[3];
    const float* b_theta = (const float*)d_in[4];
    const float* w_g     = (const float*)d_in[5];
    const float* b_g     = (const float*)d_in[6];
    const float* w_mask  = (const float*)d_in[7];
    const float* b_mask  = (const float*)d_in[8];
    float* out = (float*)d_out;

    // ws (48 MiB): [0,16M): Opart (2*8*4096*128 bf16 = 16 MiB)
    //              [16,24M): Q | [24,32M): K | [32,40M): Vt | [40M+): lsums (256 KiB)
    char* ws = (char*)d_ws;
    unsigned short* opart = (unsigned short*)(ws);
    unsigned short* qw    = (unsigned short*)(ws + ((size_t)16 << 20));
    unsigned short* kw    = (unsigned short*)(ws + ((size_t)24 << 20));
    unsigned short* vtw   = (unsigned short*)(ws + ((size_t)32 << 20));
    float*          lsums = (float*)(ws + ((size_t)40 << 20));

    k_proj<<<dim3(NN / 128, 3, BB), 256, 0, stream>>>(x, w_phi, b_phi, w_theta, b_theta,
                                                      w_g, b_g, qw, kw, vtw);
    k_flash<<<dim3(1024, 1, 1), 128, 0, stream>>>(qw, kw, vtw, opart, lsums);
    k_maskout<<<dim3(NN / 64, 2, BB), 256, 0, stream>>>(opart, lsums, w_mask, b_mask, x, out);
}